// Round 5
// baseline (349.223 us; speedup 1.0000x reference)
//
#include <hip/hip_runtime.h>
#include <math.h>

#define NT 256
constexpr int B_   = 8192;
constexpr int N_   = 100;
constexpr int E_   = 1600;
constexpr int EMB  = 5;
constexpr int XDIM = 500;    // N_*EMB
constexpr int DDIM = 2600;   // 50*52
constexpr int XWP  = 512;    // padded x-region width ([500,512) = 0)
constexpr int DOFF = 512;    // d-region start in k' space
constexpr int KPAD = 3136;   // k' total: [0,500)=x, [500,512)=0, [512,3112)=d, rest 0
constexpr int H1 = 128, H2 = 128, H3 = 64, HO = 2;

typedef short short8 __attribute__((ext_vector_type(8)));
typedef float f32x4  __attribute__((ext_vector_type(4)));

__device__ __forceinline__ float leaky(float v) { return v > 0.f ? v : 0.01f * v; }
__device__ __forceinline__ float sigm(float v)  { return 1.f / (1.f + __expf(-v)); }
__device__ __forceinline__ unsigned short f2bf(float f) {   // RNE fp32->bf16
  unsigned int x = __float_as_uint(f);
  return (unsigned short)((x + 0x7fffu + ((x >> 16) & 1u)) >> 16);
}

// ---------------- Kernel A: build CSR (dst-sorted) ----------------------------
__global__ __launch_bounds__(NT) void csr_build(
    const int* __restrict__ src, const int* __restrict__ dst,
    int* __restrict__ off_g, int* __restrict__ lst_g)
{
  __shared__ int cnt[N_ + 1];
  __shared__ int cur[N_];
  const int t = threadIdx.x;
  if (t <= N_) cnt[t] = 0;
  __syncthreads();
  for (int e = t; e < E_; e += NT) atomicAdd(&cnt[dst[e] + 1], 1);
  __syncthreads();
  if (t == 0) {
    int s = 0;
    for (int n = 0; n <= N_; ++n) { s += cnt[n]; cnt[n] = s; }
  }
  __syncthreads();
  if (t < N_) cur[t] = cnt[t];
  if (t <= N_) off_g[t] = cnt[t];
  __syncthreads();
  for (int e = t; e < E_; e += NT) {
    int d = dst[e];
    int p = atomicAdd(&cur[d], 1);
    lst_g[p] = src[e];
  }
}

// ---------------- Kernel B: prep transposed bf16 weights ----------------------
// F1T[n][k'] in remapped k' space (see constants above); F2T[n][128]; F3T[n][128]
__global__ __launch_bounds__(NT) void prep_kernel(
    const float* __restrict__ F1, const float* __restrict__ F2, const float* __restrict__ F3,
    unsigned short* __restrict__ F1T, unsigned short* __restrict__ F2T, unsigned short* __restrict__ F3T)
{
  const int b = blockIdx.x, t = threadIdx.x;
  if (b < 128) {
    for (int k = t; k < KPAD; k += NT) {
      float v = 0.f;
      if (k < XDIM)                          v = F1[(size_t)k * H1 + b];
      else if (k >= DOFF && k < DOFF + DDIM) v = F1[(size_t)(k - DOFF + XDIM) * H1 + b];
      F1T[(size_t)b * KPAD + k] = f2bf(v);
    }
  } else if (b < 256) {
    int n = b - 128;
    if (t < 128) F2T[n * 128 + t] = f2bf(F2[(size_t)t * H2 + n]);
  } else {
    int n = b - 256;
    if (n < 64 && t < 128) F3T[n * 128 + t] = f2bf(F3[(size_t)t * H3 + n]);
  }
}

// ---------------- Kernel C: fused 3-layer gated RGCN (gather) -----------------
constexpr int BT = 4;
constexpr int NP = 8;
constexpr int HS = N_ * NP;

__global__ __launch_bounds__(NT) void gnn_kernel(
    const float* __restrict__ data,
    const int* __restrict__ off_g, const int* __restrict__ lst_g,
    const float* __restrict__ W0, const float* __restrict__ b0, const float* __restrict__ G0, const float* __restrict__ gb0,
    const float* __restrict__ W1, const float* __restrict__ b1, const float* __restrict__ G1, const float* __restrict__ gb1,
    const float* __restrict__ W2, const float* __restrict__ b2, const float* __restrict__ G2, const float* __restrict__ gb2,
    unsigned short* __restrict__ xw)
{
  __shared__ float bufA[BT][HS];
  __shared__ float bufB[BT][HS];
  __shared__ int   soff[N_ + 1];
  __shared__ int   slst[E_];
  __shared__ float wts[160];
  const int t  = threadIdx.x;
  const int b0_ = blockIdx.x * BT;

  for (int i = t; i < E_; i += NT) slst[i] = lst_g[i];
  if (t <= N_) soff[t] = off_g[t];
  if (t < 5)  { wts[t] = W0[t]; wts[5 + t] = b0[t]; wts[35 + t] = gb0[t]; }
  if (t < 25) { wts[10 + t] = G0[t];
                wts[40 + t] = W1[t]; wts[70 + t]  = G1[t];
                wts[100 + t] = W2[t]; wts[130 + t] = G2[t]; }
  if (t < 5)  { wts[65 + t] = b1[t]; wts[95 + t]  = gb1[t];
                wts[125 + t] = b2[t]; wts[155 + t] = gb2[t]; }
  for (int i = t; i < BT * N_; i += NT) {
    int bb = i / N_, n = i - bb * N_;
    bufA[bb][n] = data[(size_t)(b0_ + bb) * N_ + n];
  }
  __syncthreads();

  for (int i = t; i < BT * N_; i += NT) {
    int bb = i / N_, n = i - bb * N_;
    float a = 0.f;
    int s = soff[n], e = soff[n + 1];
    for (int q = s; q < e; ++q) a += bufA[bb][slst[q]];
    float4 o; o.x = a * wts[0] + wts[5]; o.y = a * wts[1] + wts[6];
    o.z = a * wts[2] + wts[7]; o.w = a * wts[3] + wts[8];
    *(float4*)&bufB[bb][n * NP] = o;
    bufB[bb][n * NP + 4] = a * wts[4] + wts[9];
  }
  __syncthreads();

#define GATE_PHASE(RB, WA, GOF, GBOF)                                          \
  for (int i = t; i < BT * N_; i += NT) {                                      \
    int bb = i / N_, n = i - bb * N_;                                          \
    float4 h4 = *(const float4*)&RB[bb][n * NP];                               \
    float hv[5] = {h4.x, h4.y, h4.z, h4.w, RB[bb][n * NP + 4]};                \
    float ov[5];                                                               \
    _Pragma("unroll")                                                          \
    for (int j = 0; j < 5; ++j) {                                              \
      float g = wts[(GBOF) + j];                                               \
      _Pragma("unroll")                                                        \
      for (int k = 0; k < 5; ++k) g += hv[k] * wts[(GOF) + k * 5 + j];         \
      ov[j] = leaky(sigm(g) * hv[j]);                                          \
    }                                                                          \
    float4 o; o.x = ov[0]; o.y = ov[1]; o.z = ov[2]; o.w = ov[3];              \
    *(float4*)&WA[bb][n * NP] = o;                                             \
    WA[bb][n * NP + 4] = ov[4];                                                \
  }

#define LIN_PHASE(RA, WB, WOF, BOF)                                            \
  for (int i = t; i < BT * N_; i += NT) {                                      \
    int bb = i / N_, n = i - bb * N_;                                          \
    float acc[5] = {0.f, 0.f, 0.f, 0.f, 0.f};                                  \
    int s = soff[n], e = soff[n + 1];                                          \
    for (int q = s; q < e; ++q) {                                              \
      int sp = slst[q] * NP;                                                   \
      float4 v4 = *(const float4*)&RA[bb][sp];                                 \
      acc[0] += v4.x; acc[1] += v4.y; acc[2] += v4.z; acc[3] += v4.w;          \
      acc[4] += RA[bb][sp + 4];                                                \
    }                                                                          \
    float ov[5];                                                               \
    _Pragma("unroll")                                                          \
    for (int j = 0; j < 5; ++j) {                                              \
      float v = wts[(BOF) + j];                                                \
      _Pragma("unroll")                                                        \
      for (int k = 0; k < 5; ++k) v += acc[k] * wts[(WOF) + k * 5 + j];        \
      ov[j] = v;                                                               \
    }                                                                          \
    float4 o; o.x = ov[0]; o.y = ov[1]; o.z = ov[2]; o.w = ov[3];              \
    *(float4*)&WB[bb][n * NP] = o;                                             \
    WB[bb][n * NP + 4] = ov[4];                                                \
  }

  GATE_PHASE(bufB, bufA, 10, 35)
  __syncthreads();
  LIN_PHASE(bufA, bufB, 40, 65)
  __syncthreads();
  GATE_PHASE(bufB, bufA, 70, 95)
  __syncthreads();
  LIN_PHASE(bufA, bufB, 100, 125)
  __syncthreads();
  GATE_PHASE(bufB, bufA, 130, 155)
  __syncthreads();

  // store padded rows: xw[b][0..500)=h, [500,512)=0  (coalesced ushort)
  for (int i = t; i < BT * XWP; i += NT) {
    int bb = i >> 9, r = i & (XWP - 1);
    unsigned short v = 0;
    if (r < XDIM) { int n = r / 5, j = r - n * 5; v = f2bf(bufA[bb][n * NP + j]); }
    xw[(size_t)(b0_ + bb) * XWP + r] = v;
  }
#undef GATE_PHASE
#undef LIN_PHASE
}

// ---------------- Kernel D: barrier-free streaming MFMA GEMM1 + fused tail ----
// BM=32, grid 256 (1 block/CU), 4 waves; wave w owns cols w*32..+31 and all 32
// rows (2 M-frags x 2 N-frags). A/B fragments loaded directly from k-major
// global arrays (16B/lane contiguous) -- no LDS, no __syncthreads in K-loop.
constexpr int MBM = 32;
constexpr int EST = 136;

__global__ __launch_bounds__(NT) void mlp_kernel(
    const unsigned short* __restrict__ xw, const float* __restrict__ dd,
    const unsigned short* __restrict__ F1T, const float* __restrict__ fb1,
    const unsigned short* __restrict__ F2T, const float* __restrict__ fb2,
    const unsigned short* __restrict__ F3T, const float* __restrict__ fb3,
    const float* __restrict__ F4, const float* __restrict__ fb4,
    float* __restrict__ out)
{
  __shared__ __attribute__((aligned(16))) unsigned short sH[MBM * EST]; // 8.7 KB
  __shared__ float sh3[MBM * 68];                                      // 8.7 KB

  const int t    = threadIdx.x;
  const int row0 = blockIdx.x * MBM;
  const int lane = t & 63;
  const int w    = t >> 6;
  const int quad = lane >> 4;
  const int ln   = lane & 15;
  const int q8   = quad * 8;

  const unsigned short* xw0 = xw + (size_t)(row0 + ln) * XWP + q8;
  const unsigned short* xw1 = xw0 + (size_t)16 * XWP;
  const float*          dd0 = dd + (size_t)(row0 + ln) * DDIM + q8;
  const float*          dd1 = dd0 + (size_t)16 * DDIM;
  const unsigned short* bt0 = F1T + (size_t)(w * 32 + ln) * KPAD + q8;
  const unsigned short* bt1 = bt0 + (size_t)16 * KPAD;

  union U8 { unsigned u[4]; short8 s; };

  // A-fragment load in remapped k' space; kk is wave-uniform, multiple of 32.
  auto ldA = [&](const unsigned short* xp, const float* dp, int kk) -> short8 {
    if (kk < DOFF) return *(const short8*)(xp + kk);      // bf16 x-region (padded)
    int kd = kk - DOFF;
    float4 f0 = make_float4(0.f, 0.f, 0.f, 0.f), f1 = f0;
    if (kd + q8 + 8 <= DDIM) {                            // tail chunk lane-predicate
      f0 = *(const float4*)(dp + kd);
      f1 = *(const float4*)(dp + kd + 4);
    }
    U8 r;   // truncate fp32->bf16 (3 ops / pair)
    r.u[0] = (__float_as_uint(f0.y) & 0xffff0000u) | (__float_as_uint(f0.x) >> 16);
    r.u[1] = (__float_as_uint(f0.w) & 0xffff0000u) | (__float_as_uint(f0.z) >> 16);
    r.u[2] = (__float_as_uint(f1.y) & 0xffff0000u) | (__float_as_uint(f1.x) >> 16);
    r.u[3] = (__float_as_uint(f1.w) & 0xffff0000u) | (__float_as_uint(f1.z) >> 16);
    return r.s;
  };

#define LOAD2(AA, BB, c)                                                       \
  {                                                                            \
    int k0_ = (c) * 64;                                                        \
    _Pragma("unroll")                                                          \
    for (int s_ = 0; s_ < 2; ++s_) {                                           \
      int kk_ = k0_ + s_ * 32;                                                 \
      AA[s_][0] = ldA(xw0, dd0, kk_);                                          \
      AA[s_][1] = ldA(xw1, dd1, kk_);                                          \
      BB[s_][0] = *(const short8*)(bt0 + kk_);                                 \
      BB[s_][1] = *(const short8*)(bt1 + kk_);                                 \
    }                                                                          \
  }

  f32x4 acc[2][2] = {{{0.f,0.f,0.f,0.f},{0.f,0.f,0.f,0.f}},
                     {{0.f,0.f,0.f,0.f},{0.f,0.f,0.f,0.f}}};
  short8 cA[2][2], cB[2][2], nA[2][2], nB[2][2];

  LOAD2(cA, cB, 0)
  for (int c = 0; c < 49; ++c) {
    if (c + 1 < 49) LOAD2(nA, nB, c + 1)
#pragma unroll
    for (int s = 0; s < 2; ++s)
#pragma unroll
      for (int mh = 0; mh < 2; ++mh) {
        acc[mh][0] = __builtin_amdgcn_mfma_f32_16x16x32_bf16(cA[s][mh], cB[s][0], acc[mh][0], 0, 0, 0);
        acc[mh][1] = __builtin_amdgcn_mfma_f32_16x16x32_bf16(cA[s][mh], cB[s][1], acc[mh][1], 0, 0, 0);
      }
#pragma unroll
    for (int s = 0; s < 2; ++s)
#pragma unroll
      for (int x = 0; x < 2; ++x) { cA[s][x] = nA[s][x]; cB[s][x] = nB[s][x]; }
  }
#undef LOAD2

  // ---- epilogue: h1 -> (transpose via LDS) -> F2 -> F3 -> F4+sigmoid ----
  const int col0 = w * 32 + ln;
  {
    float bb0 = fb1[col0], bb1 = fb1[col0 + 16];
#pragma unroll
    for (int mh = 0; mh < 2; ++mh)
#pragma unroll
      for (int r = 0; r < 4; ++r) {
        int m = mh * 16 + quad * 4 + r;
        sH[m * EST + col0]      = f2bf(leaky(acc[mh][0][r] + bb0));
        sH[m * EST + col0 + 16] = f2bf(leaky(acc[mh][1][r] + bb1));
      }
  }
  __syncthreads();

  // h2 = leaky(h1 @ F2 + fb2), B-frags streamed from global F2T (L2-resident)
  f32x4 a2[2][2] = {{{0.f,0.f,0.f,0.f},{0.f,0.f,0.f,0.f}},
                    {{0.f,0.f,0.f,0.f},{0.f,0.f,0.f,0.f}}};
  {
    const unsigned short* g2a = F2T + (size_t)col0 * H2 + q8;
    const unsigned short* g2b = g2a + (size_t)16 * H2;
#pragma unroll
    for (int s = 0; s < 4; ++s) {
      short8 b0f = *(const short8*)(g2a + s * 32);
      short8 b1f = *(const short8*)(g2b + s * 32);
#pragma unroll
      for (int mh = 0; mh < 2; ++mh) {
        short8 af = *(const short8*)(sH + (mh * 16 + ln) * EST + s * 32 + q8);
        a2[mh][0] = __builtin_amdgcn_mfma_f32_16x16x32_bf16(af, b0f, a2[mh][0], 0, 0, 0);
        a2[mh][1] = __builtin_amdgcn_mfma_f32_16x16x32_bf16(af, b1f, a2[mh][1], 0, 0, 0);
      }
    }
  }
  __syncthreads();
  {
    float bb0 = fb2[col0], bb1 = fb2[col0 + 16];
#pragma unroll
    for (int mh = 0; mh < 2; ++mh)
#pragma unroll
      for (int r = 0; r < 4; ++r) {
        int m = mh * 16 + quad * 4 + r;
        sH[m * EST + col0]      = f2bf(leaky(a2[mh][0][r] + bb0));
        sH[m * EST + col0 + 16] = f2bf(leaky(a2[mh][1][r] + bb1));
      }
  }
  __syncthreads();

  // h3 = leaky(h2 @ F3 + fb3): N=64, wave w -> cols w*16..+15
  f32x4 a3[2] = {{0.f,0.f,0.f,0.f},{0.f,0.f,0.f,0.f}};
  {
    const unsigned short* g3 = F3T + (size_t)(w * 16 + ln) * H2 + q8;
#pragma unroll
    for (int s = 0; s < 4; ++s) {
      short8 bf = *(const short8*)(g3 + s * 32);
#pragma unroll
      for (int mh = 0; mh < 2; ++mh) {
        short8 af = *(const short8*)(sH + (mh * 16 + ln) * EST + s * 32 + q8);
        a3[mh] = __builtin_amdgcn_mfma_f32_16x16x32_bf16(af, bf, a3[mh], 0, 0, 0);
      }
    }
  }
  {
    int col = w * 16 + ln;
    float bb = fb3[col];
#pragma unroll
    for (int mh = 0; mh < 2; ++mh)
#pragma unroll
      for (int r = 0; r < 4; ++r)
        sh3[(mh * 16 + quad * 4 + r) * 68 + col] = leaky(a3[mh][r] + bb);
  }
  __syncthreads();

  // out = sigmoid(h3 @ F4 + fb4): 32 rows x 2
  if (t < MBM * HO) {
    int m = t >> 1, j = t & 1;
    float a = fb4[j];
#pragma unroll 8
    for (int k = 0; k < H3; ++k) a += sh3[m * 68 + k] * F4[k * HO + j];
    out[(size_t)(row0 + m) * HO + j] = sigm(a);
  }
}

// ---------------- launch ------------------------------------------------------
extern "C" void kernel_launch(void* const* d_in, const int* in_sizes, int n_in,
                              void* d_out, int out_size, void* d_ws, size_t ws_size,
                              hipStream_t stream) {
  const float* data = (const float*)d_in[0];
  const float* dmat = (const float*)d_in[1];
  const int*   src  = (const int*)d_in[2];
  const int*   dst  = (const int*)d_in[3];
  const float* W0 = (const float*)d_in[4];  const float* b0 = (const float*)d_in[5];
  const float* G0 = (const float*)d_in[6];  const float* gb0 = (const float*)d_in[7];
  const float* W1 = (const float*)d_in[8];  const float* b1 = (const float*)d_in[9];
  const float* G1 = (const float*)d_in[10]; const float* gb1 = (const float*)d_in[11];
  const float* W2 = (const float*)d_in[12]; const float* b2 = (const float*)d_in[13];
  const float* G2 = (const float*)d_in[14]; const float* gb2 = (const float*)d_in[15];
  const float* F1 = (const float*)d_in[16]; const float* fb1 = (const float*)d_in[17];
  const float* F2 = (const float*)d_in[18]; const float* fb2 = (const float*)d_in[19];
  const float* F3 = (const float*)d_in[20]; const float* fb3 = (const float*)d_in[21];
  const float* F4 = (const float*)d_in[22]; const float* fb4 = (const float*)d_in[23];
  float* out = (float*)d_out;

  unsigned short* xw  = (unsigned short*)d_ws;          // 8192*512 bf16 (8.4 MB)
  unsigned short* F1T = xw + (size_t)B_ * XWP;          // 128*3136
  unsigned short* F2T = F1T + 128 * KPAD;               // 128*128
  unsigned short* F3T = F2T + 128 * 128;                // 64*128
  int* off_g = (int*)(F3T + 64 * 128);                  // 101 (pad 104)
  int* lst_g = off_g + 104;                             // 1600

  csr_build<<<1, NT, 0, stream>>>(src, dst, off_g, lst_g);
  prep_kernel<<<320, NT, 0, stream>>>(F1, F2, F3, F1T, F2T, F3T);
  gnn_kernel<<<B_ / BT, NT, 0, stream>>>(data, off_g, lst_g,
                                         W0, b0, G0, gb0,
                                         W1, b1, G1, gb1,
                                         W2, b2, G2, gb2, xw);
  mlp_kernel<<<B_ / MBM, NT, 0, stream>>>(xw, dmat, F1T, fb1, F2T, fb2,
                                          F3T, fb3, F4, fb4, out);
}

// Round 6
// 323.395 us; speedup vs baseline: 1.0799x; 1.0799x over previous
//
#include <hip/hip_runtime.h>
#include <math.h>

#define NT 256
constexpr int B_   = 8192;
constexpr int N_   = 100;
constexpr int E_   = 1600;
constexpr int EMB  = 5;
constexpr int XDIM = 500;    // N_*EMB
constexpr int DDIM = 2600;   // 50*52
constexpr int XWP  = 512;    // padded x-region width ([500,512) = 0)
constexpr int DOFF = 512;    // d-region start in k' space
constexpr int KPAD = 3136;   // k': [0,500)=x, [500,512)=0, [512,3112)=d, rest 0
constexpr int H1 = 128, H2 = 128, H3 = 64, HO = 2;

typedef short short8 __attribute__((ext_vector_type(8)));
typedef float f32x4  __attribute__((ext_vector_type(4)));

__device__ __forceinline__ float leaky(float v) { return v > 0.f ? v : 0.01f * v; }
__device__ __forceinline__ float sigm(float v)  { return 1.f / (1.f + __expf(-v)); }
__device__ __forceinline__ unsigned short f2bf(float f) {   // RNE fp32->bf16
  unsigned int x = __float_as_uint(f);
  return (unsigned short)((x + 0x7fffu + ((x >> 16) & 1u)) >> 16);
}

// ---------------- Kernel A: build CSR (dst-sorted) ----------------------------
__global__ __launch_bounds__(NT) void csr_build(
    const int* __restrict__ src, const int* __restrict__ dst,
    int* __restrict__ off_g, int* __restrict__ lst_g)
{
  __shared__ int cnt[N_ + 1];
  __shared__ int cur[N_];
  const int t = threadIdx.x;
  if (t <= N_) cnt[t] = 0;
  __syncthreads();
  for (int e = t; e < E_; e += NT) atomicAdd(&cnt[dst[e] + 1], 1);
  __syncthreads();
  if (t == 0) {
    int s = 0;
    for (int n = 0; n <= N_; ++n) { s += cnt[n]; cnt[n] = s; }
  }
  __syncthreads();
  if (t < N_) cur[t] = cnt[t];
  if (t <= N_) off_g[t] = cnt[t];
  __syncthreads();
  for (int e = t; e < E_; e += NT) {
    int d = dst[e];
    int p = atomicAdd(&cur[d], 1);
    lst_g[p] = src[e];
  }
}

// ---------------- Kernel B: prep transposed bf16 weights ----------------------
__global__ __launch_bounds__(NT) void prep_kernel(
    const float* __restrict__ F1, const float* __restrict__ F2, const float* __restrict__ F3,
    unsigned short* __restrict__ F1T, unsigned short* __restrict__ F2T, unsigned short* __restrict__ F3T)
{
  const int b = blockIdx.x, t = threadIdx.x;
  if (b < 128) {
    for (int k = t; k < KPAD; k += NT) {
      float v = 0.f;
      if (k < XDIM)                          v = F1[(size_t)k * H1 + b];
      else if (k >= DOFF && k < DOFF + DDIM) v = F1[(size_t)(k - DOFF + XDIM) * H1 + b];
      F1T[(size_t)b * KPAD + k] = f2bf(v);
    }
  } else if (b < 256) {
    int n = b - 128;
    if (t < 128) F2T[n * 128 + t] = f2bf(F2[(size_t)t * H2 + n]);
  } else {
    int n = b - 256;
    if (n < 64 && t < 128) F3T[n * 128 + t] = f2bf(F3[(size_t)t * H3 + n]);
  }
}

// ---------------- Kernel C: gated RGCN, batch-along-lanes (conflict-free) -----
// BT2=32 batches per block; LDS state layout [jn = n*5+j][batch b] fp32, so
// addr = jn*32 + b -> bank = b: any wave access with b in the low lane bits is
// conflict-free (2 lanes/bank = free). One fused phase per layer:
// thread owns (n, b), gathers acc[5] from old state, applies W/bias/gate,
// writes new state to the other buffer. 1 barrier per layer.
constexpr int BT2 = 32;

// wts layout: [0..4] W0, [5..9] b0, [10..34] G0, [35..39] gb0,
// L1 base 40 / L2 base 100: W +0..24, b +25..29, G +30..54, gb +55..59
__device__ __forceinline__ void rgcn_layer(
    const float* __restrict__ RB, float* __restrict__ WB,
    const float* __restrict__ wts, const int* __restrict__ soff,
    const int* __restrict__ sl160, int t, int wof)
{
  for (int i = t; i < N_ * BT2; i += NT) {
    int n = i >> 5, b = i & 31;
    float a0 = 0.f, a1 = 0.f, a2 = 0.f, a3 = 0.f, a4 = 0.f;
    int qe = soff[n + 1];
    for (int q = soff[n]; q < qe; ++q) {
      int base = sl160[q] + b;
      a0 += RB[base];
      a1 += RB[base + 32];
      a2 += RB[base + 64];
      a3 += RB[base + 96];
      a4 += RB[base + 128];
    }
    float a[5] = {a0, a1, a2, a3, a4};
    float h2[5];
#pragma unroll
    for (int j = 0; j < 5; ++j) {
      float v = wts[wof + 25 + j];
#pragma unroll
      for (int k = 0; k < 5; ++k) v += a[k] * wts[wof + k * 5 + j];
      h2[j] = v;
    }
#pragma unroll
    for (int j = 0; j < 5; ++j) {
      float g = wts[wof + 55 + j];
#pragma unroll
      for (int k = 0; k < 5; ++k) g += h2[k] * wts[wof + 30 + k * 5 + j];
      WB[n * 160 + j * 32 + b] = leaky(sigm(g) * h2[j]);
    }
  }
}

__global__ __launch_bounds__(NT) void gnn_kernel(
    const float* __restrict__ data,
    const int* __restrict__ off_g, const int* __restrict__ lst_g,
    const float* __restrict__ W0, const float* __restrict__ b0, const float* __restrict__ G0, const float* __restrict__ gb0,
    const float* __restrict__ W1, const float* __restrict__ b1, const float* __restrict__ G1, const float* __restrict__ gb1,
    const float* __restrict__ W2, const float* __restrict__ b2, const float* __restrict__ G2, const float* __restrict__ gb2,
    unsigned short* __restrict__ xw)
{
  __shared__ float bufA[XDIM * BT2];   // 64 KB
  __shared__ float bufB[XDIM * BT2];   // 64 KB
  __shared__ int   soff[N_ + 1];
  __shared__ int   sl160[E_];          // src*160 (row offset in state array)
  __shared__ float wts[160];
  const int t   = threadIdx.x;
  const int b0_ = blockIdx.x * BT2;

  for (int i = t; i < E_; i += NT) sl160[i] = lst_g[i] * 160;
  if (t <= N_) soff[t] = off_g[t];
  if (t < 5)  { wts[t] = W0[t]; wts[5 + t] = b0[t]; wts[35 + t] = gb0[t]; }
  if (t < 25) { wts[10 + t] = G0[t];
                wts[40 + t] = W1[t]; wts[70 + t]  = G1[t];
                wts[100 + t] = W2[t]; wts[130 + t] = G2[t]; }
  if (t < 5)  { wts[65 + t] = b1[t]; wts[95 + t]  = gb1[t];
                wts[125 + t] = b2[t]; wts[155 + t] = gb2[t]; }
  // stage x into the j=0 slots of bufA: bufA[n*160 + b] = data[b0_+b][n]
  // (global read strided across 32 rows -- tiny, L3-resident; LDS write free)
  for (int i = t; i < N_ * BT2; i += NT) {
    int n = i >> 5, b = i & 31;
    bufA[n * 160 + b] = data[(size_t)(b0_ + b) * N_ + n];
  }
  __syncthreads();

  // ---- Layer 0 (scalar input): gather j=0 slots, expand to 5 channels ----
  for (int i = t; i < N_ * BT2; i += NT) {
    int n = i >> 5, b = i & 31;
    float a = 0.f;
    int qe = soff[n + 1];
    for (int q = soff[n]; q < qe; ++q) a += bufA[sl160[q] + b];
    float h2[5];
#pragma unroll
    for (int j = 0; j < 5; ++j) h2[j] = a * wts[j] + wts[5 + j];
#pragma unroll
    for (int j = 0; j < 5; ++j) {
      float g = wts[35 + j];
#pragma unroll
      for (int k = 0; k < 5; ++k) g += h2[k] * wts[10 + k * 5 + j];
      bufB[n * 160 + j * 32 + b] = leaky(sigm(g) * h2[j]);
    }
  }
  __syncthreads();

  rgcn_layer(bufB, bufA, wts, soff, sl160, t, 40);    // layer 1: B -> A
  __syncthreads();
  rgcn_layer(bufA, bufB, wts, soff, sl160, t, 100);   // layer 2: A -> B
  __syncthreads();

  // store from bufB: 4 bf16 per thread, batch in low lane bits (LDS free),
  // global write strided across 32 rows (8B/lane) -- acceptable, ~8.4 MB total
  for (int i = t; i < BT2 * (XWP / 4); i += NT) {     // 32 * 128
    int b = i & 31, r4 = i >> 5;
    int r = r4 * 4;
    float v0 = (r     < XDIM) ? bufB[(r    ) * 32 + b] : 0.f;
    float v1 = (r + 1 < XDIM) ? bufB[(r + 1) * 32 + b] : 0.f;
    float v2 = (r + 2 < XDIM) ? bufB[(r + 2) * 32 + b] : 0.f;
    float v3 = (r + 3 < XDIM) ? bufB[(r + 3) * 32 + b] : 0.f;
    uint2 p;
    p.x = (unsigned)f2bf(v0) | ((unsigned)f2bf(v1) << 16);
    p.y = (unsigned)f2bf(v2) | ((unsigned)f2bf(v3) << 16);
    ((uint2*)xw)[(size_t)(b0_ + b) * (XWP / 4) + r4] = p;
  }
}

// ---------------- Kernel D: streaming MFMA GEMM1 + fused tail -----------------
// BM=16 -> grid 512 (2 blocks/CU, 8 waves/CU), 4 waves; wave w owns cols
// w*32..+31 (2 N-frags), one shared M-frag (16 rows). Depth-2 register
// prefetch; no LDS/barriers in the K-loop. Divergent d-tail predicate peeled
// to the final chunk only.
constexpr int MB2 = 16;
constexpr int EST = 136;

__global__ __launch_bounds__(NT) void mlp_kernel(
    const unsigned short* __restrict__ xw, const float* __restrict__ dd,
    const unsigned short* __restrict__ F1T, const float* __restrict__ fb1,
    const unsigned short* __restrict__ F2T, const float* __restrict__ fb2,
    const unsigned short* __restrict__ F3T, const float* __restrict__ fb3,
    const float* __restrict__ F4, const float* __restrict__ fb4,
    float* __restrict__ out)
{
  __shared__ __attribute__((aligned(16))) unsigned short sH[MB2 * EST];
  __shared__ float sh3[MB2 * 68];

  const int t    = threadIdx.x;
  const int row0 = blockIdx.x * MB2;
  const int lane = t & 63;
  const int w    = t >> 6;
  const int quad = lane >> 4;
  const int ln   = lane & 15;
  const int q8   = quad * 8;

  const unsigned short* xa  = xw + (size_t)(row0 + ln) * XWP + q8;
  const float*          da  = dd + (size_t)(row0 + ln) * DDIM + q8;
  const unsigned short* bt0 = F1T + (size_t)(w * 32 + ln) * KPAD + q8;
  const unsigned short* bt1 = bt0 + (size_t)16 * KPAD;

  union U8 { unsigned u[4]; short8 s; };

  auto ldA = [&](int kk, bool tail) -> short8 {
    if (kk < DOFF) return *(const short8*)(xa + kk);   // bf16 x-region (padded)
    int kd = kk - DOFF;
    float4 f0, f1;
    if (!tail) {
      f0 = *(const float4*)(da + kd);
      f1 = *(const float4*)(da + kd + 4);
    } else {
      f0 = make_float4(0.f, 0.f, 0.f, 0.f); f1 = f0;
      if (kd + q8 + 8 <= DDIM) {
        f0 = *(const float4*)(da + kd);
        f1 = *(const float4*)(da + kd + 4);
      }
    }
    U8 r;   // truncate fp32->bf16
    r.u[0] = (__float_as_uint(f0.y) & 0xffff0000u) | (__float_as_uint(f0.x) >> 16);
    r.u[1] = (__float_as_uint(f0.w) & 0xffff0000u) | (__float_as_uint(f0.z) >> 16);
    r.u[2] = (__float_as_uint(f1.y) & 0xffff0000u) | (__float_as_uint(f1.x) >> 16);
    r.u[3] = (__float_as_uint(f1.w) & 0xffff0000u) | (__float_as_uint(f1.z) >> 16);
    return r.s;
  };

#define LOADF(Ax, Bx, c)                                                       \
  {                                                                            \
    int k0_ = (c) * 64;                                                        \
    _Pragma("unroll")                                                          \
    for (int s_ = 0; s_ < 2; ++s_) {                                           \
      int kk_ = k0_ + s_ * 32;                                                 \
      Ax[s_]    = ldA(kk_, kk_ == 3104);                                       \
      Bx[s_][0] = *(const short8*)(bt0 + kk_);                                 \
      Bx[s_][1] = *(const short8*)(bt1 + kk_);                                 \
    }                                                                          \
  }

  f32x4 acc0 = {0.f, 0.f, 0.f, 0.f};
  f32x4 acc1 = {0.f, 0.f, 0.f, 0.f};
  short8 A0[2], A1[2], B0[2][2], B1[2][2];

  LOADF(A0, B0, 0)
  LOADF(A1, B1, 1)
  for (int c = 0; c < 49; ++c) {
    if (c & 1) {
#pragma unroll
      for (int s = 0; s < 2; ++s) {
        acc0 = __builtin_amdgcn_mfma_f32_16x16x32_bf16(A1[s], B1[s][0], acc0, 0, 0, 0);
        acc1 = __builtin_amdgcn_mfma_f32_16x16x32_bf16(A1[s], B1[s][1], acc1, 0, 0, 0);
      }
      if (c + 2 < 49) LOADF(A1, B1, c + 2)
    } else {
#pragma unroll
      for (int s = 0; s < 2; ++s) {
        acc0 = __builtin_amdgcn_mfma_f32_16x16x32_bf16(A0[s], B0[s][0], acc0, 0, 0, 0);
        acc1 = __builtin_amdgcn_mfma_f32_16x16x32_bf16(A0[s], B0[s][1], acc1, 0, 0, 0);
      }
      if (c + 2 < 49) LOADF(A0, B0, c + 2)
    }
  }
#undef LOADF

  // ---- epilogue: h1 -> (LDS transpose) -> F2 -> F3 -> F4+sigmoid ----
  const int col0 = w * 32 + ln;
  {
    float bb0 = fb1[col0], bb1 = fb1[col0 + 16];
#pragma unroll
    for (int r = 0; r < 4; ++r) {
      int m = quad * 4 + r;
      sH[m * EST + col0]      = f2bf(leaky(acc0[r] + bb0));
      sH[m * EST + col0 + 16] = f2bf(leaky(acc1[r] + bb1));
    }
  }
  __syncthreads();

  // h2 = leaky(h1 @ F2 + fb2), B-frags streamed from global F2T (L2-resident)
  f32x4 a20 = {0.f, 0.f, 0.f, 0.f};
  f32x4 a21 = {0.f, 0.f, 0.f, 0.f};
  {
    const unsigned short* g2a = F2T + (size_t)col0 * H2 + q8;
    const unsigned short* g2b = g2a + (size_t)16 * H2;
#pragma unroll
    for (int s = 0; s < 4; ++s) {
      short8 b0f = *(const short8*)(g2a + s * 32);
      short8 b1f = *(const short8*)(g2b + s * 32);
      short8 af  = *(const short8*)(sH + ln * EST + s * 32 + q8);
      a20 = __builtin_amdgcn_mfma_f32_16x16x32_bf16(af, b0f, a20, 0, 0, 0);
      a21 = __builtin_amdgcn_mfma_f32_16x16x32_bf16(af, b1f, a21, 0, 0, 0);
    }
  }
  __syncthreads();
  {
    float bb0 = fb2[col0], bb1 = fb2[col0 + 16];
#pragma unroll
    for (int r = 0; r < 4; ++r) {
      int m = quad * 4 + r;
      sH[m * EST + col0]      = f2bf(leaky(a20[r] + bb0));
      sH[m * EST + col0 + 16] = f2bf(leaky(a21[r] + bb1));
    }
  }
  __syncthreads();

  // h3 = leaky(h2 @ F3 + fb3): N=64, wave w -> cols w*16..+15
  f32x4 a3 = {0.f, 0.f, 0.f, 0.f};
  {
    const unsigned short* g3 = F3T + (size_t)(w * 16 + ln) * H2 + q8;
#pragma unroll
    for (int s = 0; s < 4; ++s) {
      short8 bf = *(const short8*)(g3 + s * 32);
      short8 af = *(const short8*)(sH + ln * EST + s * 32 + q8);
      a3 = __builtin_amdgcn_mfma_f32_16x16x32_bf16(af, bf, a3, 0, 0, 0);
    }
  }
  {
    int col = w * 16 + ln;
    float bb = fb3[col];
#pragma unroll
    for (int r = 0; r < 4; ++r)
      sh3[(quad * 4 + r) * 68 + col] = leaky(a3[r] + bb);
  }
  __syncthreads();

  // out = sigmoid(h3 @ F4 + fb4): 16 rows x 2
  if (t < MB2 * HO) {
    int m = t >> 1, j = t & 1;
    float a = fb4[j];
#pragma unroll 8
    for (int k = 0; k < H3; ++k) a += sh3[m * 68 + k] * F4[k * HO + j];
    out[(size_t)(row0 + m) * HO + j] = sigm(a);
  }
}

// ---------------- launch ------------------------------------------------------
extern "C" void kernel_launch(void* const* d_in, const int* in_sizes, int n_in,
                              void* d_out, int out_size, void* d_ws, size_t ws_size,
                              hipStream_t stream) {
  const float* data = (const float*)d_in[0];
  const float* dmat = (const float*)d_in[1];
  const int*   src  = (const int*)d_in[2];
  const int*   dst  = (const int*)d_in[3];
  const float* W0 = (const float*)d_in[4];  const float* b0 = (const float*)d_in[5];
  const float* G0 = (const float*)d_in[6];  const float* gb0 = (const float*)d_in[7];
  const float* W1 = (const float*)d_in[8];  const float* b1 = (const float*)d_in[9];
  const float* G1 = (const float*)d_in[10]; const float* gb1 = (const float*)d_in[11];
  const float* W2 = (const float*)d_in[12]; const float* b2 = (const float*)d_in[13];
  const float* G2 = (const float*)d_in[14]; const float* gb2 = (const float*)d_in[15];
  const float* F1 = (const float*)d_in[16]; const float* fb1 = (const float*)d_in[17];
  const float* F2 = (const float*)d_in[18]; const float* fb2 = (const float*)d_in[19];
  const float* F3 = (const float*)d_in[20]; const float* fb3 = (const float*)d_in[21];
  const float* F4 = (const float*)d_in[22]; const float* fb4 = (const float*)d_in[23];
  float* out = (float*)d_out;

  unsigned short* xw  = (unsigned short*)d_ws;          // 8192*512 bf16 (8.4 MB)
  unsigned short* F1T = xw + (size_t)B_ * XWP;          // 128*3136
  unsigned short* F2T = F1T + 128 * KPAD;               // 128*128
  unsigned short* F3T = F2T + 128 * 128;                // 64*128
  int* off_g = (int*)(F3T + 64 * 128);                  // 101 (pad 104)
  int* lst_g = off_g + 104;                             // 1600

  csr_build<<<1, NT, 0, stream>>>(src, dst, off_g, lst_g);
  prep_kernel<<<320, NT, 0, stream>>>(F1, F2, F3, F1T, F2T, F3T);
  gnn_kernel<<<B_ / BT2, NT, 0, stream>>>(data, off_g, lst_g,
                                          W0, b0, G0, gb0,
                                          W1, b1, G1, gb1,
                                          W2, b2, G2, gb2, xw);
  mlp_kernel<<<B_ / MB2, NT, 0, stream>>>(xw, dmat, F1T, fb1, F2T, fb2,
                                          F3T, fb3, F4, fb4, out);
}

// Round 7
// 302.681 us; speedup vs baseline: 1.1538x; 1.0684x over previous
//
#include <hip/hip_runtime.h>
#include <math.h>

#define NT 256
#define NTG 1024
constexpr int B_   = 8192;
constexpr int N_   = 100;
constexpr int E_   = 1600;
constexpr int EMB  = 5;
constexpr int XDIM = 500;    // N_*EMB
constexpr int DDIM = 2600;   // 50*52
constexpr int XWP  = 512;    // padded x-region width ([500,512) = 0)
constexpr int DOFF = 512;    // d-region start in k' space
constexpr int KPAD = 3136;   // k': [0,500)=x, [500,512)=0, [512,3112)=d, rest 0
constexpr int H1 = 128, H2 = 128, H3 = 64, HO = 2;

typedef short short8 __attribute__((ext_vector_type(8)));
typedef float f32x4  __attribute__((ext_vector_type(4)));

__device__ __forceinline__ float leaky(float v) { return v > 0.f ? v : 0.01f * v; }
__device__ __forceinline__ float sigm(float v)  { return 1.f / (1.f + __expf(-v)); }
__device__ __forceinline__ unsigned short f2bf(float f) {   // RNE fp32->bf16
  unsigned int x = __float_as_uint(f);
  return (unsigned short)((x + 0x7fffu + ((x >> 16) & 1u)) >> 16);
}

// ---------------- Kernel A: build CSR (dst-sorted) ----------------------------
__global__ __launch_bounds__(NT) void csr_build(
    const int* __restrict__ src, const int* __restrict__ dst,
    int* __restrict__ off_g, int* __restrict__ lst_g)
{
  __shared__ int cnt[N_ + 1];
  __shared__ int cur[N_];
  const int t = threadIdx.x;
  if (t <= N_) cnt[t] = 0;
  __syncthreads();
  for (int e = t; e < E_; e += NT) atomicAdd(&cnt[dst[e] + 1], 1);
  __syncthreads();
  if (t == 0) {
    int s = 0;
    for (int n = 0; n <= N_; ++n) { s += cnt[n]; cnt[n] = s; }
  }
  __syncthreads();
  if (t < N_) cur[t] = cnt[t];
  if (t <= N_) off_g[t] = cnt[t];
  __syncthreads();
  for (int e = t; e < E_; e += NT) {
    int d = dst[e];
    int p = atomicAdd(&cur[d], 1);
    lst_g[p] = src[e];
  }
}

// ---------------- Kernel B: prep transposed bf16 weights ----------------------
__global__ __launch_bounds__(NT) void prep_kernel(
    const float* __restrict__ F1, const float* __restrict__ F2, const float* __restrict__ F3,
    unsigned short* __restrict__ F1T, unsigned short* __restrict__ F2T, unsigned short* __restrict__ F3T)
{
  const int b = blockIdx.x, t = threadIdx.x;
  if (b < 128) {
    for (int k = t; k < KPAD; k += NT) {
      float v = 0.f;
      if (k < XDIM)                          v = F1[(size_t)k * H1 + b];
      else if (k >= DOFF && k < DOFF + DDIM) v = F1[(size_t)(k - DOFF + XDIM) * H1 + b];
      F1T[(size_t)b * KPAD + k] = f2bf(v);
    }
  } else if (b < 256) {
    int n = b - 128;
    if (t < 128) F2T[n * 128 + t] = f2bf(F2[(size_t)t * H2 + n]);
  } else {
    int n = b - 256;
    if (n < 64 && t < 128) F3T[n * 128 + t] = f2bf(F3[(size_t)t * H3 + n]);
  }
}

// ---------------- Kernel C: gated RGCN, batch-along-lanes, 16 waves/CU --------
// BT2=32 batches per block, 1024 threads (1 block/CU but 4 waves/SIMD).
// State layout [jn=n*5+j][b]: bank = b -> conflict-free gathers.
constexpr int BT2 = 32;

__device__ __forceinline__ void rgcn_layer(
    const float* __restrict__ RB, float* __restrict__ WB,
    const float* __restrict__ wts, const int* __restrict__ soff,
    const int* __restrict__ sl160, int t, int wof)
{
  for (int i = t; i < N_ * BT2; i += NTG) {
    int n = i >> 5, b = i & 31;
    float a0 = 0.f, a1 = 0.f, a2 = 0.f, a3 = 0.f, a4 = 0.f;
    int qe = soff[n + 1];
    for (int q = soff[n]; q < qe; ++q) {
      int base = sl160[q] + b;
      a0 += RB[base];
      a1 += RB[base + 32];
      a2 += RB[base + 64];
      a3 += RB[base + 96];
      a4 += RB[base + 128];
    }
    float a[5] = {a0, a1, a2, a3, a4};
    float h2[5];
#pragma unroll
    for (int j = 0; j < 5; ++j) {
      float v = wts[wof + 25 + j];
#pragma unroll
      for (int k = 0; k < 5; ++k) v += a[k] * wts[wof + k * 5 + j];
      h2[j] = v;
    }
#pragma unroll
    for (int j = 0; j < 5; ++j) {
      float g = wts[wof + 55 + j];
#pragma unroll
      for (int k = 0; k < 5; ++k) g += h2[k] * wts[wof + 30 + k * 5 + j];
      WB[n * 160 + j * 32 + b] = leaky(sigm(g) * h2[j]);
    }
  }
}

__global__ __launch_bounds__(NTG) void gnn_kernel(
    const float* __restrict__ data,
    const int* __restrict__ off_g, const int* __restrict__ lst_g,
    const float* __restrict__ W0, const float* __restrict__ b0, const float* __restrict__ G0, const float* __restrict__ gb0,
    const float* __restrict__ W1, const float* __restrict__ b1, const float* __restrict__ G1, const float* __restrict__ gb1,
    const float* __restrict__ W2, const float* __restrict__ b2, const float* __restrict__ G2, const float* __restrict__ gb2,
    unsigned short* __restrict__ xw)
{
  __shared__ float bufA[BT2 * 513];    // 65.7 KB (state 16000 floats also fits)
  __shared__ float bufB[XDIM * BT2];   // 64 KB
  __shared__ int   soff[N_ + 1];
  __shared__ int   sl160[E_];
  __shared__ float wts[160];
  const int t   = threadIdx.x;
  const int b0_ = blockIdx.x * BT2;

  for (int i = t; i < E_; i += NTG) sl160[i] = lst_g[i] * 160;
  if (t <= N_) soff[t] = off_g[t];
  if (t < 5)  { wts[t] = W0[t]; wts[5 + t] = b0[t]; wts[35 + t] = gb0[t]; }
  if (t < 25) { wts[10 + t] = G0[t];
                wts[40 + t] = W1[t]; wts[70 + t]  = G1[t];
                wts[100 + t] = W2[t]; wts[130 + t] = G2[t]; }
  if (t < 5)  { wts[65 + t] = b1[t]; wts[95 + t]  = gb1[t];
                wts[125 + t] = b2[t]; wts[155 + t] = gb2[t]; }
  // coalesced input: 3200 contiguous floats, scatter into j=0 state slots
  for (int i = t; i < N_ * BT2; i += NTG) {
    int b = i / N_, n = i - b * N_;
    bufA[n * 160 + b] = data[(size_t)b0_ * N_ + i];
  }
  __syncthreads();

  // ---- Layer 0 (scalar input) ----
  for (int i = t; i < N_ * BT2; i += NTG) {
    int n = i >> 5, b = i & 31;
    float a = 0.f;
    int qe = soff[n + 1];
    for (int q = soff[n]; q < qe; ++q) a += bufA[sl160[q] + b];
    float h2[5];
#pragma unroll
    for (int j = 0; j < 5; ++j) h2[j] = a * wts[j] + wts[5 + j];
#pragma unroll
    for (int j = 0; j < 5; ++j) {
      float g = wts[35 + j];
#pragma unroll
      for (int k = 0; k < 5; ++k) g += h2[k] * wts[10 + k * 5 + j];
      bufB[n * 160 + j * 32 + b] = leaky(sigm(g) * h2[j]);
    }
  }
  __syncthreads();

  rgcn_layer(bufB, bufA, wts, soff, sl160, t, 40);    // layer 1: B -> A
  __syncthreads();
  rgcn_layer(bufA, bufB, wts, soff, sl160, t, 100);   // layer 2: A -> B
  __syncthreads();

  // transpose bufB[jn][b] -> bufA[b*513 + r] (write banks (b+r)%32: conflict-free)
  for (int i = t; i < BT2 * XWP; i += NTG) {
    int b = i & 31, r = i >> 5;
    bufA[b * 513 + r] = (r < XDIM) ? bufB[r * 32 + b] : 0.f;
  }
  __syncthreads();

  // coalesced store: thread -> (b, 8 consecutive r), 16B/lane, 1KB/wave row
  for (int i = t; i < BT2 * (XWP / 8); i += NTG) {    // 32*64 = 2048
    int r8 = i & 63, b = i >> 6;
    const float* sp = bufA + b * 513 + r8 * 8;
    uint4 p;
    p.x = (unsigned)f2bf(sp[0]) | ((unsigned)f2bf(sp[1]) << 16);
    p.y = (unsigned)f2bf(sp[2]) | ((unsigned)f2bf(sp[3]) << 16);
    p.z = (unsigned)f2bf(sp[4]) | ((unsigned)f2bf(sp[5]) << 16);
    p.w = (unsigned)f2bf(sp[6]) | ((unsigned)f2bf(sp[7]) << 16);
    ((uint4*)xw)[(size_t)(b0_ + b) * (XWP / 8) + r8] = p;
  }
}

// ---------------- Kernel D: split-K streaming MFMA GEMM1 ----------------------
// KSPLIT=4, BM=16: grid 2048 = 8 blocks/CU = 32 waves/CU. No LDS, no barriers.
// Each block computes a K-quarter partial of h1 (pre-bias) -> part[split].
constexpr int MB2 = 16;
constexpr int EST = 136;
constexpr int KSPLIT = 4;
constexpr int SC = 13;               // chunks per split (13,13,13,10 of 49)

__global__ __launch_bounds__(NT) void mlp_main(
    const unsigned short* __restrict__ xw, const float* __restrict__ dd,
    const unsigned short* __restrict__ F1T, float* __restrict__ part)
{
  const int t     = threadIdx.x;
  const int rb    = blockIdx.x & 511;
  const int split = blockIdx.x >> 9;
  const int row0  = rb * MB2;
  const int lane  = t & 63;
  const int w     = t >> 6;
  const int quad  = lane >> 4;
  const int ln    = lane & 15;
  const int q8    = quad * 8;
  const int cbeg  = split * SC;
  const int cend  = (cbeg + SC < 49) ? cbeg + SC : 49;

  const unsigned short* xa  = xw + (size_t)(row0 + ln) * XWP + q8;
  const float*          da  = dd + (size_t)(row0 + ln) * DDIM + q8;
  const unsigned short* bt0 = F1T + (size_t)(w * 32 + ln) * KPAD + q8;
  const unsigned short* bt1 = bt0 + (size_t)16 * KPAD;

  union U8 { unsigned u[4]; short8 s; };

  auto ldA = [&](int kk, bool tail) -> short8 {
    if (kk < DOFF) return *(const short8*)(xa + kk);   // bf16 x-region (padded)
    int kd = kk - DOFF;
    float4 f0, f1;
    if (!tail) {
      f0 = *(const float4*)(da + kd);
      f1 = *(const float4*)(da + kd + 4);
    } else {
      f0 = make_float4(0.f, 0.f, 0.f, 0.f); f1 = f0;
      if (kd + q8 + 8 <= DDIM) {
        f0 = *(const float4*)(da + kd);
        f1 = *(const float4*)(da + kd + 4);
      }
    }
    U8 r;   // truncate fp32->bf16
    r.u[0] = (__float_as_uint(f0.y) & 0xffff0000u) | (__float_as_uint(f0.x) >> 16);
    r.u[1] = (__float_as_uint(f0.w) & 0xffff0000u) | (__float_as_uint(f0.z) >> 16);
    r.u[2] = (__float_as_uint(f1.y) & 0xffff0000u) | (__float_as_uint(f1.x) >> 16);
    r.u[3] = (__float_as_uint(f1.w) & 0xffff0000u) | (__float_as_uint(f1.z) >> 16);
    return r.s;
  };

#define LOADF(Ax, Bx, c)                                                       \
  {                                                                            \
    int k0_ = (c) * 64;                                                        \
    _Pragma("unroll")                                                          \
    for (int s_ = 0; s_ < 2; ++s_) {                                           \
      int kk_ = k0_ + s_ * 32;                                                 \
      Ax[s_]    = ldA(kk_, kk_ == 3104);                                       \
      Bx[s_][0] = *(const short8*)(bt0 + kk_);                                 \
      Bx[s_][1] = *(const short8*)(bt1 + kk_);                                 \
    }                                                                          \
  }

  f32x4 acc0 = {0.f, 0.f, 0.f, 0.f};
  f32x4 acc1 = {0.f, 0.f, 0.f, 0.f};
  short8 A0[2], A1[2], B0[2][2], B1[2][2];

  LOADF(A0, B0, cbeg)
  LOADF(A1, B1, cbeg + 1)
  for (int c = cbeg; c < cend; ++c) {
    if ((c - cbeg) & 1) {
#pragma unroll
      for (int s = 0; s < 2; ++s) {
        acc0 = __builtin_amdgcn_mfma_f32_16x16x32_bf16(A1[s], B1[s][0], acc0, 0, 0, 0);
        acc1 = __builtin_amdgcn_mfma_f32_16x16x32_bf16(A1[s], B1[s][1], acc1, 0, 0, 0);
      }
      if (c + 2 < cend) LOADF(A1, B1, c + 2)
    } else {
#pragma unroll
      for (int s = 0; s < 2; ++s) {
        acc0 = __builtin_amdgcn_mfma_f32_16x16x32_bf16(A0[s], B0[s][0], acc0, 0, 0, 0);
        acc1 = __builtin_amdgcn_mfma_f32_16x16x32_bf16(A0[s], B0[s][1], acc1, 0, 0, 0);
      }
      if (c + 2 < cend) LOADF(A0, B0, c + 2)
    }
  }
#undef LOADF

  // store partial (pre-bias): quad-contiguous 64B segments
  const int col0 = w * 32 + ln;
  float* pp = part + ((size_t)split * B_ + row0) * H1;
#pragma unroll
  for (int r = 0; r < 4; ++r) {
    int m = quad * 4 + r;
    pp[m * H1 + col0]      = acc0[r];
    pp[m * H1 + col0 + 16] = acc1[r];
  }
}

// ---------------- Kernel E: partial-sum + fused MLP tail ----------------------
__global__ __launch_bounds__(NT) void tail_kernel(
    const float* __restrict__ part, const float* __restrict__ fb1,
    const unsigned short* __restrict__ F2T, const float* __restrict__ fb2,
    const unsigned short* __restrict__ F3T, const float* __restrict__ fb3,
    const float* __restrict__ F4, const float* __restrict__ fb4,
    float* __restrict__ out)
{
  __shared__ __attribute__((aligned(16))) unsigned short sH[MB2 * EST];
  __shared__ float sh3[MB2 * 68];

  const int t    = threadIdx.x;
  const int row0 = blockIdx.x * MB2;
  const int lane = t & 63;
  const int w    = t >> 6;
  const int quad = lane >> 4;
  const int ln   = lane & 15;
  const int q8   = quad * 8;
  constexpr size_t PS = (size_t)B_ * H1;

  // h1 = leaky(sum partials + fb1) -> sH
  for (int i = t; i < MB2 * H1; i += NT) {
    int m = i >> 7, col = i & 127;
    size_t off = (size_t)(row0 + m) * H1 + col;
    float v = part[off] + part[PS + off] + part[2 * PS + off] + part[3 * PS + off];
    sH[m * EST + col] = f2bf(leaky(v + fb1[col]));
  }
  __syncthreads();

  const int col0 = w * 32 + ln;
  // h2 = leaky(h1 @ F2 + fb2)
  f32x4 a20 = {0.f, 0.f, 0.f, 0.f};
  f32x4 a21 = {0.f, 0.f, 0.f, 0.f};
  {
    const unsigned short* g2a = F2T + (size_t)col0 * H2 + q8;
    const unsigned short* g2b = g2a + (size_t)16 * H2;
#pragma unroll
    for (int s = 0; s < 4; ++s) {
      short8 b0f = *(const short8*)(g2a + s * 32);
      short8 b1f = *(const short8*)(g2b + s * 32);
      short8 af  = *(const short8*)(sH + ln * EST + s * 32 + q8);
      a20 = __builtin_amdgcn_mfma_f32_16x16x32_bf16(af, b0f, a20, 0, 0, 0);
      a21 = __builtin_amdgcn_mfma_f32_16x16x32_bf16(af, b1f, a21, 0, 0, 0);
    }
  }
  __syncthreads();
  {
    float bb0 = fb2[col0], bb1 = fb2[col0 + 16];
#pragma unroll
    for (int r = 0; r < 4; ++r) {
      int m = quad * 4 + r;
      sH[m * EST + col0]      = f2bf(leaky(a20[r] + bb0));
      sH[m * EST + col0 + 16] = f2bf(leaky(a21[r] + bb1));
    }
  }
  __syncthreads();

  // h3 = leaky(h2 @ F3 + fb3): N=64
  f32x4 a3 = {0.f, 0.f, 0.f, 0.f};
  {
    const unsigned short* g3 = F3T + (size_t)(w * 16 + ln) * H2 + q8;
#pragma unroll
    for (int s = 0; s < 4; ++s) {
      short8 bf = *(const short8*)(g3 + s * 32);
      short8 af = *(const short8*)(sH + ln * EST + s * 32 + q8);
      a3 = __builtin_amdgcn_mfma_f32_16x16x32_bf16(af, bf, a3, 0, 0, 0);
    }
  }
  {
    int col = w * 16 + ln;
    float bb = fb3[col];
#pragma unroll
    for (int r = 0; r < 4; ++r)
      sh3[(quad * 4 + r) * 68 + col] = leaky(a3[r] + bb);
  }
  __syncthreads();

  // out = sigmoid(h3 @ F4 + fb4)
  if (t < MB2 * HO) {
    int m = t >> 1, j = t & 1;
    float a = fb4[j];
#pragma unroll 8
    for (int k = 0; k < H3; ++k) a += sh3[m * 68 + k] * F4[k * HO + j];
    out[(size_t)(row0 + m) * HO + j] = sigm(a);
  }
}

// ---------------- launch ------------------------------------------------------
extern "C" void kernel_launch(void* const* d_in, const int* in_sizes, int n_in,
                              void* d_out, int out_size, void* d_ws, size_t ws_size,
                              hipStream_t stream) {
  const float* data = (const float*)d_in[0];
  const float* dmat = (const float*)d_in[1];
  const int*   src  = (const int*)d_in[2];
  const int*   dst  = (const int*)d_in[3];
  const float* W0 = (const float*)d_in[4];  const float* b0 = (const float*)d_in[5];
  const float* G0 = (const float*)d_in[6];  const float* gb0 = (const float*)d_in[7];
  const float* W1 = (const float*)d_in[8];  const float* b1 = (const float*)d_in[9];
  const float* G1 = (const float*)d_in[10]; const float* gb1 = (const float*)d_in[11];
  const float* W2 = (const float*)d_in[12]; const float* b2 = (const float*)d_in[13];
  const float* G2 = (const float*)d_in[14]; const float* gb2 = (const float*)d_in[15];
  const float* F1 = (const float*)d_in[16]; const float* fb1 = (const float*)d_in[17];
  const float* F2 = (const float*)d_in[18]; const float* fb2 = (const float*)d_in[19];
  const float* F3 = (const float*)d_in[20]; const float* fb3 = (const float*)d_in[21];
  const float* F4 = (const float*)d_in[22]; const float* fb4 = (const float*)d_in[23];
  float* out = (float*)d_out;

  unsigned short* xw  = (unsigned short*)d_ws;          // 8192*512 bf16 (8.4 MB)
  unsigned short* F1T = xw + (size_t)B_ * XWP;          // 128*3136
  unsigned short* F2T = F1T + 128 * KPAD;               // 128*128
  unsigned short* F3T = F2T + 128 * 128;                // 64*128
  int* off_g = (int*)(F3T + 64 * 128);                  // 101 (pad 104)
  int* lst_g = off_g + 104;                             // 1600
  float* part = (float*)(lst_g + 1600);                 // 4*8192*128 fp32 (16.8 MB)

  csr_build<<<1, NT, 0, stream>>>(src, dst, off_g, lst_g);
  prep_kernel<<<320, NT, 0, stream>>>(F1, F2, F3, F1T, F2T, F3T);
  gnn_kernel<<<B_ / BT2, NTG, 0, stream>>>(data, off_g, lst_g,
                                           W0, b0, G0, gb0,
                                           W1, b1, G1, gb1,
                                           W2, b2, G2, gb2, xw);
  mlp_main<<<(B_ / MB2) * KSPLIT, NT, 0, stream>>>(xw, dmat, F1T, part);
  tail_kernel<<<B_ / MB2, NT, 0, stream>>>(part, fb1, F2T, fb2,
                                           F3T, fb3, F4, fb4, out);
}